// Round 7
// baseline (148.139 us; speedup 1.0000x reference)
//
#include <hip/hip_runtime.h>
#include <hip/hip_bf16.h>
#include <cstddef>

#define NB 2048
#define TENC 168
#define TPRED 24

typedef _Float16 h8 __attribute__((ext_vector_type(8)));
typedef float f4v __attribute__((ext_vector_type(4)));

#define MFMA16(a, b, c) __builtin_amdgcn_mfma_f32_16x16x32_f16((a), (b), (c), 0, 0, 0)

// gated = tanh(a) * sigmoid(g) with 2 exp2 + 1 rcp (denominators merged).
__device__ __forceinline__ float gate_fast(float a, float g) {
  a = fminf(a, 15.0f);
  const float e2a = __builtin_amdgcn_exp2f(a * 2.88539008177793f);    // e^(2a)
  const float eg  = __builtin_amdgcn_exp2f(g * -1.44269504088896f);   // e^(-g)
  return (e2a - 1.0f) * __builtin_amdgcn_rcpf((e2a + 1.0f) * (1.0f + eg));
}
__device__ __forceinline__ float tanh_fast(float u) {
  const float e2 = __builtin_amdgcn_exp2f(fminf(u, 15.0f) * 2.88539008177793f);
  return (e2 - 1.0f) * __builtin_amdgcn_rcpf(e2 + 1.0f);
}

// Spin until f[0..3] >= tgt. Monotonic counters; bounded guard avoids hangs.
__device__ __forceinline__ void poll4(volatile int* f, int tgt) {
  int guard = 0;
  while (f[0] < tgt || f[1] < tgt || f[2] < tgt || f[3] < tgt) {
    __builtin_amdgcn_s_sleep(1);
    if (++guard > 200000) break;
  }
  asm volatile("" ::: "memory");   // no LDS reads hoisted above the poll
}

// Publish: all prior DS ops of this wave retired, then write the flag.
#define FLAG_SET(slotp, v)                                  \
  do {                                                      \
    asm volatile("s_waitcnt lgkmcnt(0)" ::: "memory");      \
    if (ln == 0) *(volatile int*)(slotp) = (v);             \
  } while (0)

// ---------------------------------------------------------------------------
// Phase 1 (round 7): wave-specialized recurrent decoder, NO s_barrier in loop.
// 128 blocks x 512 threads, block owns 16 elements.
// Producers (waves 0-3): per layer: poll -> read gated_{l-1} -> Z += g@W43
//   -> dc = Z + S_l -> gate -> write gated_l -> pflag. Pure LDS/MFMA/VALU.
// Consumers (waves 4-7): per step: S_l = state_l@W2+b2 for all l (sflag);
//   enc/feat prefetch; embed(t+1) (eflag); lagged out-GEMM l=1..5 of step t-1;
//   l=0 of step t (state_0(t)=x_1(t-1) deadline) -> ring slot0 (qflag).
// Flags (monotonic): pflag[4]=6t+l+1 ; sflag[4]=t+1 ; eflag[4]=t+1 (embed(t)
//   ready) ; qflag[4]=t+1 (consumer stream t done). Hazard coverage:
//   S WAR: producer reads S(t) before pflag=6t+1; consumer writes S(t+1) after
//     qflag>=t+1 which requires pflag>=6t+1.   g16v WAR: 2x6 buffers + qflag.
//   ring slot0 WAR: l0(t) write waits sflag_all>=t+1 (all S(t) reads done).
//   xf16/xf32 WAR: embed(t+2) happens after qflag>=t+1 (producer read at E(t)).
// ---------------------------------------------------------------------------
__global__ __launch_bounds__(512, 1) void dec_phase1(
    const float* __restrict__ feat,    // [2048][24][15]
    const float* __restrict__ dinit,   // [2048][1]
    const float* __restrict__ enc,     // [6][2048][168][64]
    const float* __restrict__ W1,      // [16][64]
    const float* __restrict__ b1,      // [64]
    const float* __restrict__ W2,      // [64][128]
    const float* __restrict__ b2,      // [128]
    const float* __restrict__ W3,      // [64][128]
    const float* __restrict__ W4,      // [64][128]
    const float* __restrict__ b4,      // [128]
    _Float16* __restrict__ skbuf,      // [2048*24][384] f16
    int t_steps)                       // runtime 24: blocks t-loop unroll
{
  __shared__ _Float16 ring[23][16][72];    // 52.9 KB dilation rings
  __shared__ _Float16 g16v[2][6][16][72];  // 27.0 KB gated, [step-parity][layer]
  __shared__ _Float16 xf16[2][16][72];     //  4.5 KB embed (step-parity dbuf)
  __shared__ float    xf32[2][64][20];     // 10.0 KB embed f32 [parity][col][el]
  __shared__ float    S32[6][2][64][20];   // 60.0 KB S_l = state@W2+b2 [l][fg][col][el]
  __shared__ int      flags[16];           // P=0..3 S=4..7 E=8..11 Q=12..15

  const int tid = threadIdx.x;
  const int w   = tid >> 6;
  const int ln  = tid & 63;
  const int i   = ln & 15;
  const int q   = ln >> 4;
  const int q8  = q * 8;
  const int e0  = blockIdx.x * 16;

  // -------- prologue 1: stage W3 / W4res (f32) in ring region --------
  float* W3s  = (float*)&ring[0][0][0];   // [64][128] 32 KB
  float* W4rs = W3s + 64 * 128;           // [64][64]  16 KB
  for (int idx = tid; idx < 2048; idx += 512)
    ((float4*)W3s)[idx] = ((const float4*)W3)[idx];
  for (int idx = tid; idx < 1024; idx += 512) {
    const int row = idx >> 4, seg = idx & 15;
    *(float4*)&W4rs[row * 64 + seg * 4] = *(const float4*)&W4[row * 128 + 64 + seg * 4];
  }
  __syncthreads();

  // -------- prologue 2: W43 = W4res @ W3 (f16), parked in S32 region --------
  _Float16* W43h = (_Float16*)&S32[0][0][0][0];   // [64][136], 17.4 KB
  {
    const int c = tid & 127, k0 = (tid >> 7) << 4;
    float acc[16];
    #pragma unroll
    for (int r = 0; r < 16; ++r) acc[r] = 0.0f;
    for (int m = 0; m < 64; ++m) {
      const float w3v = W3s[m * 128 + c];
      #pragma unroll
      for (int r = 0; r < 16; ++r) acc[r] += W4rs[(k0 + r) * 64 + m] * w3v;
    }
    #pragma unroll
    for (int r = 0; r < 16; ++r) W43h[(k0 + r) * 136 + c] = (_Float16)acc[r];
  }
  __syncthreads();

  // -------- prologue 3: frags, ring preload, embed(0), flags --------
  // role frags: producer BA=W3f BB=W3g BC=W43f BD=W43g ; consumer BA=W2f BB=W2g BC=W4skip BD=W4res
  h8 BA[2], BB[2], BC[2], BD[2];
  float c2f = 0.f, c2g = 0.f, c4s = 0.f, c4r = 0.f;
  float w1r[16]; float b1r = 0.f; float ini4[4] = {0.f, 0.f, 0.f, 0.f};
  const int cf = (w < 4) ? (16 * w + i) : (16 * (w - 4) + i);  // producer f-col / consumer col
  const int cg = 64 + cf;
  if (w < 4) {
    #pragma unroll
    for (int kk = 0; kk < 2; ++kk)
      #pragma unroll
      for (int j = 0; j < 8; ++j) {
        const int k = kk * 32 + q8 + j;
        BA[kk][j] = (_Float16)W3[k * 128 + cf];
        BB[kk][j] = (_Float16)W3[k * 128 + cg];
        BC[kk][j] = W43h[k * 136 + cf];
        BD[kk][j] = W43h[k * 136 + cg];
      }
  } else {
    #pragma unroll
    for (int kk = 0; kk < 2; ++kk)
      #pragma unroll
      for (int j = 0; j < 8; ++j) {
        const int k = kk * 32 + q8 + j;
        BA[kk][j] = (_Float16)W2[k * 128 + cf];
        BB[kk][j] = (_Float16)W2[k * 128 + cg];
        BC[kk][j] = (_Float16)W4[k * 128 + cf];
        BD[kk][j] = (_Float16)W4[k * 128 + cg];
      }
    c2f = b2[cf]; c2g = b2[cg]; c4s = b4[cf]; c4r = b4[cg];
    #pragma unroll
    for (int ii = 0; ii < 16; ++ii) w1r[ii] = W1[ii * 64 + ln];
    b1r = b1[ln];
    #pragma unroll
    for (int s = 0; s < 4; ++s) ini4[s] = dinit[e0 + 4 * (w - 4) + s];
  }

  // ring preload (enc tails for l<=3) — overwrites the W3s/W4rs staging.
  for (int idx = tid; idx < 1920; idx += 512) {
    const int c = idx & 7, el = (idx >> 3) & 15, s = idx >> 7;
    int l, j;
    if (s == 0)      { l = 0; j = 0; }
    else if (s < 3)  { l = 1; j = s - 1; }
    else if (s < 7)  { l = 2; j = s - 3; }
    else             { l = 3; j = s - 7; }
    const int d = 1 << l;
    const float* ep = enc + (((size_t)l * NB + e0 + el) * TENC + (TENC + j - d)) * 64 + c * 8;
    h8 hv;
    #pragma unroll
    for (int u = 0; u < 8; ++u) hv[u] = (_Float16)ep[u];
    *(h8*)&ring[s][el][c * 8] = hv;
  }
  // embed(0): all 8 waves, 2 elements each
  {
    float w1e[16];
    #pragma unroll
    for (int ii = 0; ii < 16; ++ii) w1e[ii] = W1[ii * 64 + ln];
    const float b1e = b1[ln];
    #pragma unroll
    for (int s = 0; s < 2; ++s) {
      const int el = 2 * w + s;
      const float* fp = feat + (size_t)(e0 + el) * TPRED * 15;
      float u = b1e + dinit[e0 + el] * w1e[0];
      #pragma unroll
      for (int ii = 0; ii < 15; ++ii) u += fp[ii] * w1e[ii + 1];
      const float xv = tanh_fast(u);
      xf16[0][el][ln] = (_Float16)xv;
      xf32[0][ln][el] = xv;
    }
  }
  if (tid < 16) flags[tid] = (tid >= 8 && tid < 12) ? 1 : 0;  // eflag=1: embed(0) ready
  __syncthreads();   // last barrier — flag sync from here on

  if (w < 4) {
    // ================= PRODUCER =================
    for (int t = 0; t < t_steps; ++t) {
      poll4(&flags[8],  t + 1);   // embed(t) ready
      poll4(&flags[4],  t + 1);   // S(t) ready
      poll4(&flags[12], t);       // consumer stream t-1 done (g16v/xf16 WAR)

      f4v Sf[6], Sg[6];
      #pragma unroll
      for (int l = 0; l < 6; ++l) {
        Sf[l] = *(const f4v*)&S32[l][0][cf][4 * q];
        Sg[l] = *(const f4v*)&S32[l][1][cf][4 * q];
      }
      const h8 a2 = *(const h8*)&xf16[t & 1][i][q8];
      const h8 a3 = *(const h8*)&xf16[t & 1][i][32 + q8];
      f4v Zf = {0, 0, 0, 0}, Zg = {0, 0, 0, 0};
      Zf = MFMA16(a2, BA[0], Zf); Zf = MFMA16(a3, BA[1], Zf);
      Zg = MFMA16(a2, BB[0], Zg); Zg = MFMA16(a3, BB[1], Zg);
      #pragma unroll
      for (int r = 0; r < 4; ++r)
        g16v[t & 1][0][4 * q + r][cf] =
            (_Float16)gate_fast(Zf[r] + Sf[0][r], Zg[r] + Sg[0][r]);
      FLAG_SET(&flags[w], 6 * t + 1);

      #pragma unroll
      for (int l = 1; l < 6; ++l) {
        poll4(&flags[0], 6 * t + l);   // peers finished layer l-1
        const h8 gA0 = *(const h8*)&g16v[t & 1][l - 1][i][q8];
        const h8 gA1 = *(const h8*)&g16v[t & 1][l - 1][i][32 + q8];
        Zf = MFMA16(gA0, BC[0], Zf); Zf = MFMA16(gA1, BC[1], Zf);
        Zg = MFMA16(gA0, BD[0], Zg); Zg = MFMA16(gA1, BD[1], Zg);
        #pragma unroll
        for (int r = 0; r < 4; ++r)
          g16v[t & 1][l][4 * q + r][cf] =
              (_Float16)gate_fast(Zf[r] + Sf[l][r], Zg[r] + Sg[l][r]);
        FLAG_SET(&flags[w], 6 * t + l + 1);
      }
    }
  } else {
    // ================= CONSUMER =================
    const int cw = w - 4;
    f4v p4[4], p5[4];
    {  // enc prefetch for t=0
      const float* e4 = enc + (((size_t)4 * NB + e0 + i) * TENC + 152) * 64 + q8;
      const float* e5 = enc + (((size_t)5 * NB + e0 + i) * TENC + 136) * 64 + q8;
      p4[0] = *(const f4v*)(e4);      p4[1] = *(const f4v*)(e4 + 4);
      p4[2] = *(const f4v*)(e4 + 32); p4[3] = *(const f4v*)(e4 + 36);
      p5[0] = *(const f4v*)(e5);      p5[1] = *(const f4v*)(e5 + 4);
      p5[2] = *(const f4v*)(e5 + 32); p5[3] = *(const f4v*)(e5 + 36);
    }
    f4v xregA = {0, 0, 0, 0}, xregB = {0, 0, 0, 0};

    for (int t = 0; t < t_steps; ++t) {
      // ---- pos1: S_l(t) for all layers ----
      poll4(&flags[12], t);   // all ring inputs for S(t) written
      #pragma unroll
      for (int l = 0; l < 6; ++l) {
        h8 sa0, sa1;
        if (l <= 3) {
          const int d = 1 << l, slot = (d - 1) + (t & (d - 1));
          sa0 = *(const h8*)&ring[slot][i][q8];
          sa1 = *(const h8*)&ring[slot][i][32 + q8];
        } else if (l == 4) {
          if (t < 16) {
            #pragma unroll
            for (int u = 0; u < 4; ++u) {
              sa0[u] = (_Float16)p4[0][u]; sa0[u + 4] = (_Float16)p4[1][u];
              sa1[u] = (_Float16)p4[2][u]; sa1[u + 4] = (_Float16)p4[3][u];
            }
          } else {
            const int slot = 15 + (t & 7);
            sa0 = *(const h8*)&ring[slot][i][q8];
            sa1 = *(const h8*)&ring[slot][i][32 + q8];
          }
        } else {
          #pragma unroll
          for (int u = 0; u < 4; ++u) {
            sa0[u] = (_Float16)p5[0][u]; sa0[u + 4] = (_Float16)p5[1][u];
            sa1[u] = (_Float16)p5[2][u]; sa1[u + 4] = (_Float16)p5[3][u];
          }
        }
        f4v Sfa = {c2f, c2f, c2f, c2f}, Sga = {c2g, c2g, c2g, c2g};
        Sfa = MFMA16(sa0, BA[0], Sfa); Sfa = MFMA16(sa1, BA[1], Sfa);
        Sga = MFMA16(sa0, BB[0], Sga); Sga = MFMA16(sa1, BB[1], Sga);
        *(f4v*)&S32[l][0][cf][4 * q] = Sfa;
        *(f4v*)&S32[l][1][cf][4 * q] = Sga;
      }
      FLAG_SET(&flags[4 + cw], t + 1);

      // ---- pos2: enc prefetch for t+1 ----
      if (t + 1 < t_steps) {
        if (t + 1 < 16) {
          const float* e4 = enc + (((size_t)4 * NB + e0 + i) * TENC + (152 + t + 1)) * 64 + q8;
          p4[0] = *(const f4v*)(e4);      p4[1] = *(const f4v*)(e4 + 4);
          p4[2] = *(const f4v*)(e4 + 32); p4[3] = *(const f4v*)(e4 + 36);
        }
        const float* e5 = enc + (((size_t)5 * NB + e0 + i) * TENC + (136 + t + 1)) * 64 + q8;
        p5[0] = *(const f4v*)(e5);      p5[1] = *(const f4v*)(e5 + 4);
        p5[2] = *(const f4v*)(e5 + 32); p5[3] = *(const f4v*)(e5 + 36);

        // ---- pos3: embed(t+1), 4 elements ----
        #pragma unroll
        for (int s = 0; s < 4; ++s) {
          const int el = 4 * cw + s;
          const float* fp = feat + ((size_t)(e0 + el) * TPRED + (t + 1)) * 15;
          float u = b1r + ini4[s] * w1r[0];
          #pragma unroll
          for (int ii = 0; ii < 15; ++ii) u += fp[ii] * w1r[ii + 1];
          const float xv = tanh_fast(u);
          xf16[(t + 1) & 1][el][ln] = (_Float16)xv;
          xf32[(t + 1) & 1][ln][el] = xv;
        }
        FLAG_SET(&flags[8 + cw], t + 2);
      }

      // ---- pos4: lagged out-GEMM, layers 1..5 of step t-1 ----
      if (t > 0) {
        const int s = t - 1;
        poll4(&flags[0], 6 * s + 6);   // producer finished step s
        #pragma unroll
        for (int lp = 1; lp < 6; ++lp) {
          const h8 gA0 = *(const h8*)&g16v[s & 1][lp][i][q8];
          const h8 gA1 = *(const h8*)&g16v[s & 1][lp][i][32 + q8];
          f4v osk = {c4s, c4s, c4s, c4s};
          osk = MFMA16(gA0, BC[0], osk); osk = MFMA16(gA1, BC[1], osk);
          #pragma unroll
          for (int r = 0; r < 4; ++r)
            skbuf[((size_t)(e0 + 4 * q + r) * TPRED + s) * 384 + lp * 64 + cf] =
                (_Float16)fmaxf(osk[r], 0.0f);
          if (lp < 5) {
            f4v ore = {c4r, c4r, c4r, c4r};
            ore = MFMA16(gA0, BD[0], ore); ore = MFMA16(gA1, BD[1], ore);
            const int dlp = 1 << lp;
            const int slot = (lp <= 3) ? (dlp - 1) + (s & (dlp - 1)) : 15 + (s & 7);
            const bool wr = (lp <= 3) || (s <= 7);
            #pragma unroll
            for (int r = 0; r < 4; ++r) {
              xregA[r] += ore[r];
              if (wr) ring[slot][4 * q + r][cf] = (_Float16)xregA[r];
            }
          }
        }
      }

      // ---- pos5: layer 0 of step t (deadline: ring slot0 for t+1) ----
      poll4(&flags[4], t + 1);       // all S(t) reads of slot0 done (WAR)
      poll4(&flags[0], 6 * t + 1);   // producer L0(t) done
      {
        const h8 gA0 = *(const h8*)&g16v[t & 1][0][i][q8];
        const h8 gA1 = *(const h8*)&g16v[t & 1][0][i][32 + q8];
        f4v osk = {c4s, c4s, c4s, c4s}, ore = {c4r, c4r, c4r, c4r};
        osk = MFMA16(gA0, BC[0], osk); osk = MFMA16(gA1, BC[1], osk);
        ore = MFMA16(gA0, BD[0], ore); ore = MFMA16(gA1, BD[1], ore);
        xregB = *(const f4v*)&xf32[t & 1][cf][4 * q];
        #pragma unroll
        for (int r = 0; r < 4; ++r) {
          skbuf[((size_t)(e0 + 4 * q + r) * TPRED + t) * 384 + cf] =
              (_Float16)fmaxf(osk[r], 0.0f);
          xregB[r] += ore[r];
          ring[0][4 * q + r][cf] = (_Float16)xregB[r];
        }
      }
      FLAG_SET(&flags[12 + cw], t + 1);
      xregA = xregB;
    }

    // ---- drain: lagged layers 1..5 of the final step ----
    {
      const int s = t_steps - 1;
      poll4(&flags[0], 6 * s + 6);
      #pragma unroll
      for (int lp = 1; lp < 6; ++lp) {
        const h8 gA0 = *(const h8*)&g16v[s & 1][lp][i][q8];
        const h8 gA1 = *(const h8*)&g16v[s & 1][lp][i][32 + q8];
        f4v osk = {c4s, c4s, c4s, c4s};
        osk = MFMA16(gA0, BC[0], osk); osk = MFMA16(gA1, BC[1], osk);
        #pragma unroll
        for (int r = 0; r < 4; ++r)
          skbuf[((size_t)(e0 + 4 * q + r) * TPRED + s) * 384 + lp * 64 + cf] =
              (_Float16)fmaxf(osk[r], 0.0f);
      }
    }
  }
}

// ---------------------------------------------------------------------------
// Phase 2: y = relu( sk @ W5 + b5 ) @ W6 + b6, 49152 rows, f16 MFMA.
// 512 blocks x 96 rows; 76.5 KB LDS -> 2 blocks/CU.
// ---------------------------------------------------------------------------
__global__ __launch_bounds__(512, 1) void dec_phase2(
    const _Float16* __restrict__ skbuf,  // [49152][384] f16 (already relu'd)
    const float* __restrict__ W5,        // [384][128]
    const float* __restrict__ b5,        // [128]
    const float* __restrict__ W6,        // [128]
    const float* __restrict__ b6,        // [1]
    float* __restrict__ out)             // [49152]
{
  __shared__ _Float16 As[96][392];       // 73.5 KB
  __shared__ float red[96][8];           // 3 KB

  const int tid = threadIdx.x;
  const int w   = tid >> 6;
  const int ln  = tid & 63;
  const int i   = ln & 15;
  const int q   = ln >> 4;
  const int R0  = blockIdx.x * 96;
  const int col = 16 * w + i;

  h8 B5[12];
  #pragma unroll
  for (int kk = 0; kk < 12; ++kk)
    #pragma unroll
    for (int j = 0; j < 8; ++j)
      B5[kk][j] = (_Float16)W5[(size_t)(kk * 32 + q * 8 + j) * 128 + col];
  const float b5r = b5[col], w6r = W6[col];

  #pragma unroll
  for (int it = 0; it < 9; ++it) {
    const int idx = tid + it * 512;            // 0..4607 = 96 rows x 48 segs
    const h8 v = *(const h8*)&skbuf[(size_t)(R0 + idx / 48) * 384 + (idx % 48) * 8];
    *(h8*)&As[idx / 48][(idx % 48) * 8] = v;
  }
  __syncthreads();

  #pragma unroll
  for (int m = 0; m < 6; ++m) {
    f4v acc = {0, 0, 0, 0};
    #pragma unroll
    for (int kk = 0; kk < 12; ++kk) {
      const h8 a = *(const h8*)&As[16 * m + i][kk * 32 + q * 8];
      acc = MFMA16(a, B5[kk], acc);
    }
    float py[4];
    #pragma unroll
    for (int r = 0; r < 4; ++r)
      py[r] = fmaxf(acc[r] + b5r, 0.0f) * w6r;
    #pragma unroll
    for (int r = 0; r < 4; ++r) {
      float v = py[r];
      v += __shfl_xor(v, 1);
      v += __shfl_xor(v, 2);
      v += __shfl_xor(v, 4);
      v += __shfl_xor(v, 8);
      py[r] = v;
    }
    if (i == 0) {
      #pragma unroll
      for (int r = 0; r < 4; ++r) red[16 * m + 4 * q + r][w] = py[r];
    }
  }
  __syncthreads();

  if (tid < 96) {
    const f4v r0 = *(const f4v*)&red[tid][0];
    const f4v r1 = *(const f4v*)&red[tid][4];
    out[R0 + tid] = b6[0] + r0[0] + r0[1] + r0[2] + r0[3]
                          + r1[0] + r1[1] + r1[2] + r1[3];
  }
}

extern "C" void kernel_launch(void* const* d_in, const int* in_sizes, int n_in,
                              void* d_out, int out_size, void* d_ws, size_t ws_size,
                              hipStream_t stream) {
  const float* feat  = (const float*)d_in[0];
  const float* dinit = (const float*)d_in[1];
  const float* enc   = (const float*)d_in[2];
  const float* W1    = (const float*)d_in[3];
  const float* b1    = (const float*)d_in[4];
  const float* W2    = (const float*)d_in[5];
  const float* b2    = (const float*)d_in[6];
  const float* W3    = (const float*)d_in[7];
  const float* W4    = (const float*)d_in[8];
  const float* b4    = (const float*)d_in[9];
  const float* W5    = (const float*)d_in[10];
  const float* b5    = (const float*)d_in[11];
  const float* W6    = (const float*)d_in[12];
  const float* b6    = (const float*)d_in[13];

  float*     out   = (float*)d_out;
  _Float16*  skbuf = (_Float16*)d_ws;   // 49152*384*2 = 37.7 MB workspace

  dec_phase1<<<dim3(128), dim3(512), 0, stream>>>(
      feat, dinit, enc, W1, b1, W2, b2, W3, W4, b4, skbuf, TPRED);
  dec_phase2<<<dim3(512), dim3(512), 0, stream>>>(
      skbuf, W5, b5, W6, b6, out);
}